// Round 4
// baseline (211.751 us; speedup 1.0000x reference)
//
#include <hip/hip_runtime.h>
#include <hip/hip_bf16.h>

#define DIMC 384          // C
#define LL 785            // 1 + 28*28
#define FDIM 1536         // 4*C  (GEMM K)
#define ODIM 768          // 2*C  (GEMM N)
#define NPATCH 196        // 14*14
#define MROWS 12544       // B*196 (GEMM M)
#define BATCH 64

typedef __attribute__((ext_vector_type(8))) short bf16x8;
typedef __attribute__((ext_vector_type(4))) float floatx4;
typedef __attribute__((ext_vector_type(4))) unsigned short ushort4v;

// ws layout (bytes):
//   anorm u16[12544*1536] @ 0           (38,535,168 B)  pre-normalized bf16 A
//   wbf   u16[768*1536]   @ 38535168    ( 2,359,296 B)  bf16(gamma * w_red)
//   bias  f32[768]        @ 40894464    (     3,072 B)  sum_f beta*w_red
#define WS_WBF_OFF  38535168
#define WS_BIAS_OFF 40894464

__device__ __forceinline__ unsigned short f2bf(float f) {
  union { float f; unsigned int u; } v; v.f = f;
  unsigned int u = v.u + 0x7fffu + ((v.u >> 16) & 1u);   // RNE
  return (unsigned short)(u >> 16);
}

__device__ __forceinline__ void gload_lds16(const void* g, void* l) {
  __builtin_amdgcn_global_load_lds(
      (const __attribute__((address_space(1))) unsigned int*)g,
      (__attribute__((address_space(3))) unsigned int*)l, 16, 0, 0);
}

// ---------------------------------------------------------------------------
// Prep kernel (block ranges by role):
//  [0,1568)      norm: one wave per TWO m-rows (12 loads in flight, two
//                interleaved butterfly chains). Loads are two contiguous
//                768-float runs per row (pixel pair (2i,2j..2j+1) and
//                (2i+1,2j..2j+1)); the quadrant reorder happens on the
//                store side (still coalesced in two 512B segments).
//  [1568,2720)   wbf:  wbf[o][f] = bf16(gamma[f] * w_red[o][f])
//  [2720,2912)   bias: bias[o] = sum_f beta[f] * w_red[o][f]
//  [2912,3104)   cls:  out[b,0,o] = dot(x[b,0,:], w_conv[o,:])
// ---------------------------------------------------------------------------
__global__ __launch_bounds__(256) void prep_kernel(
    const float* __restrict__ x, const float* __restrict__ wred,
    const float* __restrict__ wconv, const float* __restrict__ gamma,
    const float* __restrict__ beta, unsigned short* __restrict__ anorm,
    unsigned short* __restrict__ wbf, float* __restrict__ bias,
    float* __restrict__ out) {
  const int blk = blockIdx.x;
  const int t = threadIdx.x;
  const int wv = t >> 6;
  const int lane = t & 63;

  if (blk < 1568) {                      // ---- norm: 2 rows per wave ----
    const int w = blk * 4 + wv;          // 0..6271
    const int lane4 = lane * 4;
    float4 v[2][6];                      // [row][chunk0:0..2, chunk1:3..5]
    unsigned int base0[2];
#pragma unroll
    for (int rr = 0; rr < 2; ++rr) {
      int m = w * 2 + rr;
      int b = m / NPATCH;
      int n = m - b * NPATCH;
      int i = n / 14;
      int j = n - i * 14;
      base0[rr] = ((unsigned)b * LL + 1 + (unsigned)(i * 2) * 28 + (unsigned)(j * 2)) * DIMC;
    }
    // Issue all 12 independent loads first.
#pragma unroll
    for (int rr = 0; rr < 2; ++rr) {
#pragma unroll
      for (int c = 0; c < 3; ++c) {
        v[rr][c]     = *reinterpret_cast<const float4*>(x + base0[rr] + lane4 + c * 256);
        v[rr][3 + c] = *reinterpret_cast<const float4*>(x + base0[rr] + 28 * DIMC + lane4 + c * 256);
      }
    }
    float s[2] = {0.f, 0.f}, s2[2] = {0.f, 0.f};
#pragma unroll
    for (int rr = 0; rr < 2; ++rr)
#pragma unroll
      for (int c = 0; c < 6; ++c) {
        float4 q = v[rr][c];
        s[rr]  += q.x + q.y + q.z + q.w;
        s2[rr] += q.x * q.x + q.y * q.y + q.z * q.z + q.w * q.w;
      }
    // Two independent butterfly chains, interleaved for ILP.
#pragma unroll
    for (int o = 1; o < 64; o <<= 1) {
      s[0]  += __shfl_xor(s[0], o);
      s[1]  += __shfl_xor(s[1], o);
      s2[0] += __shfl_xor(s2[0], o);
      s2[1] += __shfl_xor(s2[1], o);
    }
#pragma unroll
    for (int rr = 0; rr < 2; ++rr) {
      int m = w * 2 + rr;
      float mu = s[rr] * (1.f / FDIM);
      float var = s2[rr] * (1.f / FDIM) - mu * mu;
      float rs = rsqrtf(var + 1e-5f);
      float nmu = -mu * rs;
      unsigned short* arow = anorm + (size_t)m * FDIM;
      // chunk0 (pixel 2i,2j|2j+1): fl<384 -> q0 (f=fl), fl>=384 -> q2 (f=fl+384)
      // chunk1 (pixel 2i+1,...):   fl<384 -> q1 (f=fl+384), fl>=384 -> q3 (f=fl+768)
#pragma unroll
      for (int c = 0; c < 6; ++c) {
        int fl = lane4 + (c % 3) * 256;
        int f = fl + ((fl >= 384) ? 384 : 0) + ((c >= 3) ? 384 : 0);
        float4 q = v[rr][c];
        union { ushort4v u4; __hip_bfloat162 h[2]; } u;
        u.h[0] = __float22bfloat162_rn(make_float2(q.x * rs + nmu, q.y * rs + nmu));
        u.h[1] = __float22bfloat162_rn(make_float2(q.z * rs + nmu, q.w * rs + nmu));
        *reinterpret_cast<ushort4v*>(arow + f) = u.u4;
      }
    }
  } else if (blk < 2720) {               // ---- wbf = bf16(gamma * w_red) ----
    int idx4 = (blk - 1568) * 256 + t;   // < 294912
    int e0 = idx4 * 4;
    int f = e0 % FDIM;
    float4 wq = *reinterpret_cast<const float4*>(wred + e0);
    float4 g = *reinterpret_cast<const float4*>(gamma + f);
    ushort4v u;
    u.x = f2bf(wq.x * g.x); u.y = f2bf(wq.y * g.y);
    u.z = f2bf(wq.z * g.z); u.w = f2bf(wq.w * g.w);
    *reinterpret_cast<ushort4v*>(wbf + e0) = u;
  } else if (blk < 2912) {               // ---- bias ----
    int o = (blk - 2720) * 4 + wv;       // < 768
    const float* wr = wred + (size_t)o * FDIM;
    float s = 0.f;
#pragma unroll
    for (int c = 0; c < 6; ++c) {
      int f = lane * 4 + c * 256;
      float4 wq = *reinterpret_cast<const float4*>(wr + f);
      float4 be = *reinterpret_cast<const float4*>(beta + f);
      s += wq.x * be.x + wq.y * be.y + wq.z * be.z + wq.w * be.w;
    }
#pragma unroll
    for (int o2 = 32; o2 > 0; o2 >>= 1) s += __shfl_down(s, o2);
    if (lane == 0) bias[o] = s;
  } else {                               // ---- cls ----
    __shared__ float xs[DIMC];
    int idx = blk - 2912;                // < 192
    int b = idx / 3;
    int ch = idx - b * 3;
    for (int c = t; c < DIMC; c += 256) xs[c] = x[(size_t)b * LL * DIMC + c];
    __syncthreads();
    int o = ch * 256 + t;
    const float* wr = wconv + (size_t)o * DIMC;
    float acc = 0.f;
#pragma unroll 4
    for (int c = 0; c < DIMC; c += 4) {
      float4 wq = *reinterpret_cast<const float4*>(wr + c);
      acc += wq.x * xs[c] + wq.y * xs[c + 1] + wq.z * xs[c + 2] + wq.w * xs[c + 3];
    }
    out[(size_t)b * 197 * ODIM + o] = acc;
  }
}

// ---------------------------------------------------------------------------
// GEMM (m97 structure): C[m,o] = sum_f anorm[m,f] * wbf[o,f] + bias[o].
// Tile 128x128, BK=64, 256 thr = 4 waves in 2x2, wave = 4x4 of 16x16x32 MFMA.
// Staging via global_load_lds width=16, XOR-swizzled LDS chunks (0 conflicts,
// verified round 3). 1-D grid with XCD-aware swizzle: the 6 column-blocks of
// one row-group share id%8 -> same XCD -> A-tile fetched into L2 once, not 6x.
// ---------------------------------------------------------------------------
__global__ __launch_bounds__(256) void gemm_kernel(
    const unsigned short* __restrict__ anorm,
    const unsigned short* __restrict__ wbf,
    const float* __restrict__ bias, float* __restrict__ out) {
  __shared__ unsigned short As[128 * 64];   // 16 KB
  __shared__ unsigned short Bs[128 * 64];   // 16 KB

  const int t = threadIdx.x;
  // XCD swizzle: 588 blocks = 12 groups of (8 rb x 6 cb) + tail (rb 96,97).
  int id = blockIdx.x;
  int rb, cb;
  if (id < 576) {
    int g = id / 48;
    int rem = id - g * 48;
    rb = g * 8 + (rem & 7);
    cb = rem >> 3;
  } else {
    int r = id - 576;
    rb = 96 + (r & 1);
    cb = r >> 1;
  }
  const int mBase = rb * 128;
  const int nBase = cb * 128;

  const unsigned short* agp[4];
  const unsigned short* bgp[4];
  unsigned int ldsoff[4];
#pragma unroll
  for (int p = 0; p < 4; ++p) {
    int s = p * 256 + t;
    int r = s >> 3;
    int cs = (s & 7) ^ (r & 7);
    agp[p] = anorm + (size_t)(mBase + r) * FDIM + cs * 8;
    bgp[p] = wbf + (size_t)(nBase + r) * FDIM + cs * 8;
    ldsoff[p] = (unsigned)s * 8;
  }

  const int wv = t >> 6;
  const int lane = t & 63;
  const int ln15 = lane & 15;
  const int quad = lane >> 4;
  const int wm = wv >> 1;
  const int wn = wv & 1;

  unsigned int aoff[4][2], boff[4][2];
#pragma unroll
  for (int mt = 0; mt < 4; ++mt) {
#pragma unroll
    for (int h = 0; h < 2; ++h) {
      int rA = wm * 64 + mt * 16 + ln15;
      aoff[mt][h] = (unsigned)(rA * 64 + (((h * 4 + quad) ^ (rA & 7)) * 8));
      int rB = wn * 64 + mt * 16 + ln15;
      boff[mt][h] = (unsigned)(rB * 64 + (((h * 4 + quad) ^ (rB & 7)) * 8));
    }
  }

  floatx4 acc[4][4];
#pragma unroll
  for (int mt = 0; mt < 4; ++mt)
#pragma unroll
    for (int nt = 0; nt < 4; ++nt)
      acc[mt][nt] = floatx4{0.f, 0.f, 0.f, 0.f};

  for (int kt = 0; kt < FDIM / 64; ++kt) {
    if (kt) __syncthreads();
#pragma unroll
    for (int p = 0; p < 4; ++p) {
      gload_lds16(agp[p], &As[ldsoff[p]]);
      gload_lds16(bgp[p], &Bs[ldsoff[p]]);
      agp[p] += 64;
      bgp[p] += 64;
    }
    __syncthreads();

#pragma unroll
    for (int h = 0; h < 2; ++h) {
      bf16x8 af[4], bfr[4];
#pragma unroll
      for (int mt = 0; mt < 4; ++mt)
        af[mt] = *reinterpret_cast<const bf16x8*>(&As[aoff[mt][h]]);
#pragma unroll
      for (int nt = 0; nt < 4; ++nt)
        bfr[nt] = *reinterpret_cast<const bf16x8*>(&Bs[boff[nt][h]]);
#pragma unroll
      for (int mt = 0; mt < 4; ++mt)
#pragma unroll
        for (int nt = 0; nt < 4; ++nt)
          acc[mt][nt] = __builtin_amdgcn_mfma_f32_16x16x32_bf16(
              af[mt], bfr[nt], acc[mt][nt], 0, 0, 0);
    }
  }

  // Epilogue. C/D: col = ln15, row = quad*4 + reg  [m89/m91].
  float bs[4];
#pragma unroll
  for (int nt = 0; nt < 4; ++nt)
    bs[nt] = bias[nBase + wn * 64 + nt * 16 + ln15];
#pragma unroll
  for (int mt = 0; mt < 4; ++mt) {
#pragma unroll
    for (int r = 0; r < 4; ++r) {
      int m = mBase + wm * 64 + mt * 16 + quad * 4 + r;
      int b = m / NPATCH;
      int n = m - b * NPATCH;
      float* orow = out + ((size_t)b * 197 + 1 + n) * ODIM + nBase + wn * 64;
#pragma unroll
      for (int nt = 0; nt < 4; ++nt)
        orow[nt * 16 + ln15] = acc[mt][nt][r] + bs[nt];
    }
  }
}

extern "C" void kernel_launch(void* const* d_in, const int* in_sizes, int n_in,
                              void* d_out, int out_size, void* d_ws, size_t ws_size,
                              hipStream_t stream) {
  const float* x     = (const float*)d_in[0];   // (64, 785, 384)
  const float* wred  = (const float*)d_in[1];   // (768, 1536)
  const float* wconv = (const float*)d_in[2];   // (768, 384)
  const float* gamma = (const float*)d_in[3];   // (1536,)
  const float* beta  = (const float*)d_in[4];   // (1536,)
  float* out = (float*)d_out;                   // (64, 197, 768)

  unsigned short* anorm = (unsigned short*)d_ws;
  unsigned short* wbf   = (unsigned short*)((char*)d_ws + WS_WBF_OFF);
  float* bias           = (float*)((char*)d_ws + WS_BIAS_OFF);

  prep_kernel<<<dim3(3104), 256, 0, stream>>>(x, wred, wconv, gamma, beta,
                                              anorm, wbf, bias, out);
  gemm_kernel<<<dim3(588), 256, 0, stream>>>(anorm, wbf, bias, out);
}